// Round 14
// baseline (93.909 us; speedup 1.0000x reference)
//
#include <hip/hip_runtime.h>

// ---------------------------------------------------------------------------
// y = x @ Q^T where Q = H_0 H_1 ... H_{N-1}, H_n = I - 2 v_n v_n^T/(v_n.v_n+eps)
// S=256, N=258, B=65536.
//
// TWO kernels (R13 model: ~8us per merge level + ~2us per launch made the
// 3-level merge tree the dominant non-gemm cost -> eliminate it):
//  hh_q:    full 258-step chain per Q-row, 64 blocks x 64 thr (4 rows/block,
//           16-lane DPP dot-reduce). v-rows staged through double-buffered
//           LDS in 31-row batches (global_load_lds, XOR-swizzled source so
//           ds_read_b128 fragment reads are conflict-free). All c_n
//           precomputed into LDS (pads=0 -> padded steps are exact no-ops).
//  hh_gemm: y = x @ Qb^T, bf16 MFMA, BM=128 BN=256 BK=32 (R13-proven).
//
// d_ws: Qb (128KB) only. d_out untouched until hh_gemm writes it.
// ---------------------------------------------------------------------------

#define GLOAD_LDS16(g, l)                                                      \
  __builtin_amdgcn_global_load_lds(                                            \
      (const __attribute__((address_space(1))) void*)(g),                      \
      (__attribute__((address_space(3))) void*)(l), 16, 0, 0)

typedef __attribute__((ext_vector_type(8))) short bf16x8;
typedef __attribute__((ext_vector_type(4))) float f32x4;

__device__ __forceinline__ unsigned short f2bf_rne(float f) {
  unsigned u = __builtin_bit_cast(unsigned, f);
  return (unsigned short)((u + 0x7fffu + ((u >> 16) & 1u)) >> 16);
}

// DPP-shuffled add: v + dpp(v). CTRL: 0xB1=quad xor1, 0x4E=quad xor2,
// 0x124=row_ror:4, 0x128=row_ror:8. Pure VALU latency, no LDS.
template <int CTRL>
__device__ __forceinline__ float dpp_add(float v) {
  int t = __builtin_amdgcn_update_dpp(0, __builtin_bit_cast(int, v), CTRL, 0xF,
                                      0xF, true);
  return v + __builtin_bit_cast(float, t);
}

// full 16-lane-group sum (all lanes get the sum)
__device__ __forceinline__ float dpp_sum16(float p) {
  p = dpp_add<0xB1>(p);
  p = dpp_add<0x4E>(p);
  p = dpp_add<0x124>(p);
  p = dpp_add<0x128>(p);
  return p;
}

// ---------------- Phase 1: full Q-row chains --------------------------------
// 64 blocks x 64 threads (1 wave). Lane l: row-group r=l>>4 (4 Q-rows/block),
// col-group cl=l&15 (16 contiguous cols/lane). 9 batches x 31 steps = 279
// steps (258 real; c=0 pads no-op). LDS: vb = 2 x [31][256] f32 (63488B)
// + cs[288] (1152B) = 64640B.
__launch_bounds__(64, 1)
__global__ void hh_q(const float* __restrict__ vecs,
                     unsigned short* __restrict__ Qb) {
  __shared__ __align__(128) char vb[63488];
  __shared__ float cs[288];

  const int l = threadIdx.x;
  const int r = l >> 4;
  const int cl = l & 15;
  const int row = blockIdx.x * 4 + r;
  const int col0 = cl * 16;

  // ---- prologue: cs[n] = 2/(v_n.v_n + eps) for n<258, 0 for pads ----------
  for (int n = r; n < 258; n += 4) {
    const f32x4* vp = (const f32x4*)(vecs + (long)n * 256 + col0);
    float s = 0.f;
#pragma unroll
    for (int i = 0; i < 4; ++i) {
      f32x4 t = vp[i];
      s += t[0] * t[0] + t[1] * t[1] + t[2] * t[2] + t[3] * t[3];
    }
    s = dpp_sum16(s);
    if (cl == 0) cs[n] = 2.0f / (s + 1e-16f);
  }
  if (l < 30) cs[258 + l] = 0.f;
  __syncthreads();

  // ---- staging: batch = 31 rows -> 31744B linear in vb[buf] ---------------
  // Source seg pre-swizzled (involution seg^((seg>>3)&7)) so fragment
  // ds_read_b128 (lane cl reads segs 4cl..4cl+3) is 2-way -> conflict-free.
  auto stage = [&](int buf, int batch) {
    const int base = batch * 31;
#pragma unroll
    for (int it = 0; it < 31; ++it) {
      int slot = it * 64 + l;
      int rw = slot >> 6, ps = slot & 63;
      int ss = ps ^ ((ps >> 3) & 7);
      int gr = base + rw;
      gr = gr > 257 ? 257 : gr;  // clamp; padded rows get c=0 -> no-op steps
      GLOAD_LDS16(vecs + (long)gr * 256 + ss * 4, vb + buf * 31744 + slot * 16);
    }
  };

  auto loadA = [&](float(&d)[16], int buf, int k) {
#pragma unroll
    for (int i = 0; i < 4; ++i) {
      int g = cl * 4 + i;
      int p = g ^ ((g >> 3) & 7);
      f32x4 t = *(const f32x4*)(vb + buf * 31744 + k * 1024 + p * 16);
      d[4 * i] = t[0]; d[4 * i + 1] = t[1];
      d[4 * i + 2] = t[2]; d[4 * i + 3] = t[3];
    }
  };

  float q[16];
#pragma unroll
  for (int i = 0; i < 16; ++i) q[i] = (col0 + i == row) ? 1.f : 0.f;

  auto step = [&](const float(&a)[16], float cc) {
    float p0 = 0.f, p1 = 0.f, p2 = 0.f, p3 = 0.f;
#pragma unroll
    for (int e = 0; e < 4; ++e) {
      p0 = fmaf(q[e], a[e], p0);
      p1 = fmaf(q[4 + e], a[4 + e], p1);
      p2 = fmaf(q[8 + e], a[8 + e], p2);
      p3 = fmaf(q[12 + e], a[12 + e], p3);
    }
    const float p = dpp_sum16((p0 + p1) + (p2 + p3));
    const float s = cc * p;
#pragma unroll
    for (int k2 = 0; k2 < 16; ++k2) q[k2] = fmaf(-s, a[k2], q[k2]);
  };

  stage(0, 0);
  asm volatile("s_waitcnt vmcnt(0)" ::: "memory");
  float A[2][16];
  loadA(A[0], 0, 0);
  loadA(A[1], 0, 1);
  stage(1, 1);

  int curbuf = 0;
  for (int b = 0; b < 9; ++b) {
    const int b31 = b * 31;
    float ccv[2] = {cs[b31], cs[b31 + 1]};
#pragma unroll
    for (int k = 0; k < 31; ++k) {
      step(A[k & 1], ccv[k & 1]);
      ccv[k & 1] = cs[b31 + k + 2];          // <= cs[280], pads zeroed
      if (k + 2 < 31) loadA(A[k & 1], curbuf, k + 2);
    }
    if (b < 8) {
      asm volatile("s_waitcnt vmcnt(0)" ::: "memory");  // stage(b+1) done
      loadA(A[0], curbuf ^ 1, 0);
      loadA(A[1], curbuf ^ 1, 1);
      if (b + 2 <= 8) stage(curbuf, b + 2);  // WAR-safe: reads already issued
      curbuf ^= 1;
    }
  }

#pragma unroll
  for (int i = 0; i < 16; ++i) Qb[row * 256 + col0 + i] = f2bf_rne(q[i]);
}

// ---------------- Phase 3: GEMM --------------------------------------------
// C[M=65536][256] = A[M][K=256](f32, cvt->bf16) * B[N=256][K=256](bf16, BT)
// Block: BM=128, BN=256, BK=32, 512 thr (8 waves). Wave grid 2x4, 64x64/wave.
// LDS 64KB dbuf; XOR-swizzled staging via pre-swizzled GLOBAL source address.
__launch_bounds__(512)
__global__ void hh_gemm(const float* __restrict__ X,
                        const unsigned short* __restrict__ Qb,
                        float* __restrict__ Y) {
  __shared__ __align__(128) char lds[65536];
  const int tid = threadIdx.x;
  const int lane = tid & 63;
  const int wid = tid >> 6;
  const int wm = wid >> 2;  // 0..1
  const int wn = wid & 3;   // 0..3
  const int fr = lane & 15;
  const int fg = lane >> 4;
  const long bm0 = (long)blockIdx.x * 128;

  auto stage = [&](int buf, int kt) {
#pragma unroll
    for (int r2 = 0; r2 < 2; ++r2) {
      int slot = r2 * 512 + tid;
      int row = slot >> 3, seg = slot & 7;
      int ps = seg ^ (row & 7);
      GLOAD_LDS16(X + (bm0 + row) * 256 + kt * 32 + ps * 4,
                  lds + buf * 16384 + slot * 16);
    }
#pragma unroll
    for (int r2 = 0; r2 < 2; ++r2) {
      int slot = r2 * 512 + tid;
      int row = slot >> 2, seg = slot & 3;
      int ps = seg ^ (row & 3);
      GLOAD_LDS16(Qb + row * 256 + kt * 32 + ps * 8,
                  lds + 32768 + buf * 16384 + slot * 16);
    }
  };

  f32x4 acc[4][4];
#pragma unroll
  for (int m = 0; m < 4; ++m)
#pragma unroll
    for (int n = 0; n < 4; ++n) acc[m][n] = (f32x4){0.f, 0.f, 0.f, 0.f};

  stage(0, 0);
  __syncthreads();

  for (int kt = 0; kt < 8; ++kt) {
    const int cur = kt & 1;
    if (kt < 7) stage(cur ^ 1, kt + 1);

    bf16x8 aF[4], bF[4];
#pragma unroll
    for (int m = 0; m < 4; ++m) {
      int row = wm * 64 + m * 16 + fr;
      int s0 = (2 * fg) ^ (row & 7);
      int s1 = (2 * fg + 1) ^ (row & 7);
      const f32x4 x0 = *(const f32x4*)(lds + cur * 16384 + row * 128 + s0 * 16);
      const f32x4 x1 = *(const f32x4*)(lds + cur * 16384 + row * 128 + s1 * 16);
      bf16x8 t;
      t[0] = (short)f2bf_rne(x0[0]);
      t[1] = (short)f2bf_rne(x0[1]);
      t[2] = (short)f2bf_rne(x0[2]);
      t[3] = (short)f2bf_rne(x0[3]);
      t[4] = (short)f2bf_rne(x1[0]);
      t[5] = (short)f2bf_rne(x1[1]);
      t[6] = (short)f2bf_rne(x1[2]);
      t[7] = (short)f2bf_rne(x1[3]);
      aF[m] = t;
    }
#pragma unroll
    for (int n = 0; n < 4; ++n) {
      int row = wn * 64 + n * 16 + fr;
      int ps = fg ^ (row & 3);
      bF[n] = *(const bf16x8*)(lds + 32768 + cur * 16384 + row * 64 + ps * 16);
    }
#pragma unroll
    for (int m = 0; m < 4; ++m)
#pragma unroll
      for (int n = 0; n < 4; ++n)
        acc[m][n] =
            __builtin_amdgcn_mfma_f32_16x16x32_bf16(aF[m], bF[n], acc[m][n], 0, 0, 0);
    __syncthreads();
  }

#pragma unroll
  for (int m = 0; m < 4; ++m)
#pragma unroll
    for (int n = 0; n < 4; ++n)
#pragma unroll
      for (int r = 0; r < 4; ++r) {
        long grow = bm0 + wm * 64 + m * 16 + fg * 4 + r;
        int gcol = wn * 64 + n * 16 + fr;
        Y[grow * 256 + gcol] = acc[m][n][r];
      }
}

// ---------------------------------------------------------------------------
extern "C" void kernel_launch(void* const* d_in, const int* in_sizes, int n_in,
                              void* d_out, int out_size, void* d_ws, size_t ws_size,
                              hipStream_t stream) {
  const float* x = (const float*)d_in[0];      // [65536][256] f32
  const float* vecs = (const float*)d_in[1];   // [258][256] f32
  float* y = (float*)d_out;                    // [65536][256] f32

  unsigned short* Qb = (unsigned short*)d_ws;  // 256x256 bf16 (128KB)

  hh_q<<<64, 64, 0, stream>>>(vecs, Qb);
  hh_gemm<<<512, 512, 0, stream>>>(x, Qb, y);
}

// Round 15
// 74.557 us; speedup vs baseline: 1.2596x; 1.2596x over previous
//
#include <hip/hip_runtime.h>

// ---------------------------------------------------------------------------
// y = x @ Q^T where Q = H_0 H_1 ... H_{N-1}, H_n = I - 2 v_n v_n^T/(v_n.v_n+eps)
// S=256, N=258, B=65536.
//
// THREE kernels. Calibrated budget (R14 gave gemm ~= 11us via hh_q=82.3 of
// 93.9 total; re-solving R8/R12/R13: mm level ~= 12us, chain ~= 180cy/step):
//  hh_qchunk: 2 chunks x 129 steps (129*2 = 258 exactly), 128 blocks x 64 thr,
//             R13-proven structure: fused norm prologue into LDS, direct-L2
//             v loads w/ 2-deep register prefetch, 16-lane DPP dot-reduce.
//             (R14's LDS-staged chain was 700cy/step -- direct L2 wins.)
//  hh_mm:     ONE merge level: Q = Qc0 * Qc1 (R8-proven LDS fp32 GEMM),
//             writes bf16 Qb directly.
//  hh_gemm:   y = x @ Qb^T, bf16 MFMA, BM=128 BN=256 BK=32 (runs from L3).
//
// d_ws: Qb (128KB). Qc (512KB) in d_out scratch (dead before hh_gemm).
// ---------------------------------------------------------------------------

#define GLOAD_LDS16(g, l)                                                      \
  __builtin_amdgcn_global_load_lds(                                            \
      (const __attribute__((address_space(1))) void*)(g),                      \
      (__attribute__((address_space(3))) void*)(l), 16, 0, 0)

typedef __attribute__((ext_vector_type(8))) short bf16x8;
typedef __attribute__((ext_vector_type(4))) float f32x4;

__device__ __forceinline__ unsigned short f2bf_rne(float f) {
  unsigned u = __builtin_bit_cast(unsigned, f);
  return (unsigned short)((u + 0x7fffu + ((u >> 16) & 1u)) >> 16);
}

// DPP-shuffled add: v + dpp(v). CTRL: 0xB1=quad xor1, 0x4E=quad xor2,
// 0x124=row_ror:4, 0x128=row_ror:8. Pure VALU latency, no LDS.
template <int CTRL>
__device__ __forceinline__ float dpp_add(float v) {
  int t = __builtin_amdgcn_update_dpp(0, __builtin_bit_cast(int, v), CTRL, 0xF,
                                      0xF, true);
  return v + __builtin_bit_cast(float, t);
}

// full 16-lane-group sum (all lanes get the sum)
__device__ __forceinline__ float dpp_sum16(float p) {
  p = dpp_add<0xB1>(p);
  p = dpp_add<0x4E>(p);
  p = dpp_add<0x124>(p);
  p = dpp_add<0x128>(p);
  return p;
}

// ---------------- Phase 1: 2-chunk Q-row chains -----------------------------
// 128 blocks x 64 threads (1 wave). Block = (chunk=bx>>6, rowgroup=bx&63).
// Lane l: row-in-group r=l>>4 (4 Q-rows/block), col-group cl=l&15.
// chunk c covers H rows [129c, 129c+128] -- 129 steps, no padding.
__launch_bounds__(64, 1)
__global__ void hh_qchunk(const float* __restrict__ vecs,
                          float* __restrict__ Qc) {
  const int l = threadIdx.x;
  const int chunk = blockIdx.x >> 6;   // 0..1
  const int rg = blockIdx.x & 63;      // 0..63
  const int r = l >> 4;                // lane group 0..3
  const int cl = l & 15;               // lane in group
  const int row = rg * 4 + r;
  const int col0 = cl * 16;
  const int brow = chunk * 129;        // chunk's first global H row

  __shared__ float cs[132];

  // ---- prologue: cs[n] = 2/(v_{brow+n}.v + eps), n = 0..128; pads 0 -------
  for (int n = r; n < 129; n += 4) {
    const f32x4* vp = (const f32x4*)(vecs + (long)(brow + n) * 256 + col0);
    float s = 0.f;
#pragma unroll
    for (int i = 0; i < 4; ++i) {
      f32x4 t = vp[i];
      s += t[0] * t[0] + t[1] * t[1] + t[2] * t[2] + t[3] * t[3];
    }
    s = dpp_sum16(s);
    if (cl == 0) cs[n] = 2.0f / (s + 1e-16f);
  }
  if (l < 3) cs[129 + l] = 0.f;
  __syncthreads();

  float q[16];
#pragma unroll
  for (int i = 0; i < 16; ++i) q[i] = (col0 + i == row) ? 1.f : 0.f;

  auto load16 = [&](float(&d)[16], int n) {
    int gr = brow + n;
    gr = gr > 257 ? 257 : gr;  // only the last prefetch (n=129) clamps
    const float4* v = (const float4*)(vecs + (long)gr * 256 + col0);
#pragma unroll
    for (int i = 0; i < 4; ++i) {
      float4 t = v[i];
      d[4 * i] = t.x; d[4 * i + 1] = t.y; d[4 * i + 2] = t.z; d[4 * i + 3] = t.w;
    }
  };

  auto step = [&](const float(&a)[16], float cc) {
    float p0 = 0.f, p1 = 0.f, p2 = 0.f, p3 = 0.f;
#pragma unroll
    for (int e = 0; e < 4; ++e) {
      p0 = fmaf(q[e], a[e], p0);
      p1 = fmaf(q[4 + e], a[4 + e], p1);
      p2 = fmaf(q[8 + e], a[8 + e], p2);
      p3 = fmaf(q[12 + e], a[12 + e], p3);
    }
    const float p = dpp_sum16((p0 + p1) + (p2 + p3));
    const float s = cc * p;
#pragma unroll
    for (int k = 0; k < 16; ++k) q[k] = fmaf(-s, a[k], q[k]);
  };

  float A0[16], A1[16];
  load16(A0, 0);
  load16(A1, 1);
  float c0 = cs[0], c1 = cs[1];
  for (int n = 0; n < 128; n += 2) {
    const float cn0 = cs[n + 2], cn1 = cs[n + 3];  // <= cs[129], zeroed pad
    step(A0, c0);
    load16(A0, n + 2);   // n+2 <= 128: in-chunk
    step(A1, c1);
    load16(A1, n + 3);   // n+3 <= 129: clamped prefetch, never consumed live
    c0 = cn0; c1 = cn1;
  }
  step(A0, c0);  // step 128

  float4* out = (float4*)(Qc + (long)chunk * 65536 + row * 256 + col0);
#pragma unroll
  for (int i = 0; i < 4; ++i)
    out[i] = make_float4(q[4 * i], q[4 * i + 1], q[4 * i + 2], q[4 * i + 3]);
}

// ---------------- Phase 2: single merge (R8-proven LDS fp32 GEMM) ----------
// Qb = bf16( Qc0 * Qc1 ). Grid 64 blocks x 256 thr; 32x32 tile per block,
// 2x2 per thread, K staged via LDS in 64-wide panels.
__launch_bounds__(256)
__global__ void hh_mm(const float* __restrict__ in,
                      unsigned short* __restrict__ outb) {
  const int t = blockIdx.x;
  const int ti = (t >> 3) * 32, tj = (t & 7) * 32;
  const int tid = threadIdx.x;
  const int tx = tid & 15, ty = tid >> 4;
  const float* A = in;            // Qc0
  const float* Bm = in + 65536;   // Qc1

  __shared__ float As[32][68];  // pad 68: row-stride bank-offset for col reads
  __shared__ float Bs[64][36];  // pad 36 keeps float4 alignment

  float acc00 = 0.f, acc01 = 0.f, acc10 = 0.f, acc11 = 0.f;

  for (int k0 = 0; k0 < 256; k0 += 64) {
#pragma unroll
    for (int u0 = 0; u0 < 2048; u0 += 1024) {
      int idx = u0 + tid * 4;
      int rr = idx >> 6, cc = idx & 63;
      *(float4*)&As[rr][cc] = *(const float4*)&A[(ti + rr) * 256 + k0 + cc];
      int kk = idx >> 5, jj = idx & 31;
      *(float4*)&Bs[kk][jj] = *(const float4*)&Bm[(k0 + kk) * 256 + tj + jj];
    }
    __syncthreads();
#pragma unroll 8
    for (int kk = 0; kk < 64; ++kk) {
      float a0 = As[2 * ty][kk], a1 = As[2 * ty + 1][kk];
      float b0 = Bs[kk][2 * tx], b1 = Bs[kk][2 * tx + 1];
      acc00 = fmaf(a0, b0, acc00);
      acc01 = fmaf(a0, b1, acc01);
      acc10 = fmaf(a1, b0, acc10);
      acc11 = fmaf(a1, b1, acc11);
    }
    __syncthreads();
  }

  const int gi = ti + 2 * ty, gj = tj + 2 * tx;
  outb[gi * 256 + gj] = f2bf_rne(acc00);
  outb[gi * 256 + gj + 1] = f2bf_rne(acc01);
  outb[(gi + 1) * 256 + gj] = f2bf_rne(acc10);
  outb[(gi + 1) * 256 + gj + 1] = f2bf_rne(acc11);
}

// ---------------- Phase 3: GEMM --------------------------------------------
// C[M=65536][256] = A[M][K=256](f32, cvt->bf16) * B[N=256][K=256](bf16, BT)
// Block: BM=128, BN=256, BK=32, 512 thr (8 waves). Wave grid 2x4, 64x64/wave.
// LDS 64KB dbuf; XOR-swizzled staging via pre-swizzled GLOBAL source address.
__launch_bounds__(512)
__global__ void hh_gemm(const float* __restrict__ X,
                        const unsigned short* __restrict__ Qb,
                        float* __restrict__ Y) {
  __shared__ __align__(128) char lds[65536];
  const int tid = threadIdx.x;
  const int lane = tid & 63;
  const int wid = tid >> 6;
  const int wm = wid >> 2;  // 0..1
  const int wn = wid & 3;   // 0..3
  const int fr = lane & 15;
  const int fg = lane >> 4;
  const long bm0 = (long)blockIdx.x * 128;

  auto stage = [&](int buf, int kt) {
#pragma unroll
    for (int r2 = 0; r2 < 2; ++r2) {
      int slot = r2 * 512 + tid;
      int row = slot >> 3, seg = slot & 7;
      int ps = seg ^ (row & 7);
      GLOAD_LDS16(X + (bm0 + row) * 256 + kt * 32 + ps * 4,
                  lds + buf * 16384 + slot * 16);
    }
#pragma unroll
    for (int r2 = 0; r2 < 2; ++r2) {
      int slot = r2 * 512 + tid;
      int row = slot >> 2, seg = slot & 3;
      int ps = seg ^ (row & 3);
      GLOAD_LDS16(Qb + row * 256 + kt * 32 + ps * 8,
                  lds + 32768 + buf * 16384 + slot * 16);
    }
  };

  f32x4 acc[4][4];
#pragma unroll
  for (int m = 0; m < 4; ++m)
#pragma unroll
    for (int n = 0; n < 4; ++n) acc[m][n] = (f32x4){0.f, 0.f, 0.f, 0.f};

  stage(0, 0);
  __syncthreads();

  for (int kt = 0; kt < 8; ++kt) {
    const int cur = kt & 1;
    if (kt < 7) stage(cur ^ 1, kt + 1);

    bf16x8 aF[4], bF[4];
#pragma unroll
    for (int m = 0; m < 4; ++m) {
      int row = wm * 64 + m * 16 + fr;
      int s0 = (2 * fg) ^ (row & 7);
      int s1 = (2 * fg + 1) ^ (row & 7);
      const f32x4 x0 = *(const f32x4*)(lds + cur * 16384 + row * 128 + s0 * 16);
      const f32x4 x1 = *(const f32x4*)(lds + cur * 16384 + row * 128 + s1 * 16);
      bf16x8 t;
      t[0] = (short)f2bf_rne(x0[0]);
      t[1] = (short)f2bf_rne(x0[1]);
      t[2] = (short)f2bf_rne(x0[2]);
      t[3] = (short)f2bf_rne(x0[3]);
      t[4] = (short)f2bf_rne(x1[0]);
      t[5] = (short)f2bf_rne(x1[1]);
      t[6] = (short)f2bf_rne(x1[2]);
      t[7] = (short)f2bf_rne(x1[3]);
      aF[m] = t;
    }
#pragma unroll
    for (int n = 0; n < 4; ++n) {
      int row = wn * 64 + n * 16 + fr;
      int ps = fg ^ (row & 3);
      bF[n] = *(const bf16x8*)(lds + 32768 + cur * 16384 + row * 64 + ps * 16);
    }
#pragma unroll
    for (int m = 0; m < 4; ++m)
#pragma unroll
      for (int n = 0; n < 4; ++n)
        acc[m][n] =
            __builtin_amdgcn_mfma_f32_16x16x32_bf16(aF[m], bF[n], acc[m][n], 0, 0, 0);
    __syncthreads();
  }

#pragma unroll
  for (int m = 0; m < 4; ++m)
#pragma unroll
    for (int n = 0; n < 4; ++n)
#pragma unroll
      for (int r = 0; r < 4; ++r) {
        long grow = bm0 + wm * 64 + m * 16 + fg * 4 + r;
        int gcol = wn * 64 + n * 16 + fr;
        Y[grow * 256 + gcol] = acc[m][n][r];
      }
}

// ---------------------------------------------------------------------------
extern "C" void kernel_launch(void* const* d_in, const int* in_sizes, int n_in,
                              void* d_out, int out_size, void* d_ws, size_t ws_size,
                              hipStream_t stream) {
  const float* x = (const float*)d_in[0];      // [65536][256] f32
  const float* vecs = (const float*)d_in[1];   // [258][256] f32
  float* y = (float*)d_out;                    // [65536][256] f32

  unsigned short* Qb = (unsigned short*)d_ws;  // 256x256 bf16 (128KB)
  float* Qc = (float*)d_out;                   // 2 x 256x256 f32 scratch (512KB,
                                               // dead before hh_gemm overwrites)

  hh_qchunk<<<128, 64, 0, stream>>>(vecs, Qc);
  hh_mm<<<64, 256, 0, stream>>>(Qc, Qb);
  hh_gemm<<<512, 512, 0, stream>>>(x, Qb, y);
}

// Round 18
// 65.845 us; speedup vs baseline: 1.4262x; 1.1323x over previous
//
#include <hip/hip_runtime.h>

// ---------------------------------------------------------------------------
// y = x @ Q^T where Q = H_0 H_1 ... H_{N-1}, H_n = I - 2 v_n v_n^T/(v_n.v_n+eps)
// S=256, N=258, B=65536.
//
// THREE kernels:
//  hh_qchunk: 2 chunks x 129 steps (258 exactly), 128 blocks x 64 thr.
//             PLAIN C++ chain with 4-deep rotating register prefetch pinned
//             by __builtin_amdgcn_sched_barrier(0) after each load-issue.
//             (Asm register-tie pipeline is BANNED: 1 pass / 4 failures
//             across R5/R6/R7/R16/R17 -- allocation-fragile. sched_barrier
//             is the supported way to stop load sinking, which R15 showed
//             costs 890cy/step.) Norms computed INLINE per step (s = a.a
//             alongside p = q.a, independent DPP chains) -- no prologue.
//  hh_mm:     Qb = bf16(Qc0 * Qc1)  (R8/R13-proven LDS fp32 GEMM).
//  hh_gemm:   y = x @ Qb^T, bf16 MFMA, BM=128 BN=256 BK=32 (L3-resident,
//             ~10-11us measured by subtraction in R14/R15).
//
// d_ws: Qb (128KB). Qc (512KB) in d_out scratch (dead before hh_gemm).
// ---------------------------------------------------------------------------

#define GLOAD_LDS16(g, l)                                                      \
  __builtin_amdgcn_global_load_lds(                                            \
      (const __attribute__((address_space(1))) void*)(g),                      \
      (__attribute__((address_space(3))) void*)(l), 16, 0, 0)

typedef __attribute__((ext_vector_type(8))) short bf16x8;
typedef __attribute__((ext_vector_type(4))) float f32x4;

__device__ __forceinline__ unsigned short f2bf_rne(float f) {
  unsigned u = __builtin_bit_cast(unsigned, f);
  return (unsigned short)((u + 0x7fffu + ((u >> 16) & 1u)) >> 16);
}

// DPP-shuffled add: v + dpp(v). CTRL: 0xB1=quad xor1, 0x4E=quad xor2,
// 0x124=row_ror:4, 0x128=row_ror:8. Pure VALU latency, no LDS.
template <int CTRL>
__device__ __forceinline__ float dpp_add(float v) {
  int t = __builtin_amdgcn_update_dpp(0, __builtin_bit_cast(int, v), CTRL, 0xF,
                                      0xF, true);
  return v + __builtin_bit_cast(float, t);
}

// full 16-lane-group sum (all lanes get the sum)
__device__ __forceinline__ float dpp_sum16(float p) {
  p = dpp_add<0xB1>(p);
  p = dpp_add<0x4E>(p);
  p = dpp_add<0x124>(p);
  p = dpp_add<0x128>(p);
  return p;
}

// ---------------- Phase 1: 2-chunk Q-row chains (sched_barrier pipeline) ---
// 128 blocks x 64 threads (1 wave). Block = (chunk=bx>>6, rowgroup=bx&63).
// Lane l: row-in-group r=l>>4 (4 Q-rows/block), col-group cl=l&15
// (16 contiguous cols/lane). Chunk c: 129 steps over H rows [129c, 129c+128].
__launch_bounds__(64, 1)
__global__ void hh_qchunk(const float* __restrict__ vecs,
                          float* __restrict__ Qc) {
  const int l = threadIdx.x;
  const int chunk = blockIdx.x >> 6;   // 0..1
  const int rg = blockIdx.x & 63;      // 0..63
  const int r = l >> 4;
  const int cl = l & 15;
  const int row = rg * 4 + r;
  const int col0 = cl * 16;
  const int brow = chunk * 129;

  float q[16];
#pragma unroll
  for (int i = 0; i < 16; ++i) q[i] = (col0 + i == row) ? 1.f : 0.f;

  auto load16 = [&](float(&d)[16], int n) {
    int gr = brow + n;
    gr = gr > 257 ? 257 : gr;  // clamp: prefetches past chunk end, never consumed
    const float4* v = (const float4*)(vecs + (long)gr * 256 + col0);
#pragma unroll
    for (int i = 0; i < 4; ++i) {
      float4 t = v[i];
      d[4 * i] = t.x; d[4 * i + 1] = t.y; d[4 * i + 2] = t.z; d[4 * i + 3] = t.w;
    }
  };

  // step: p = q.a and s = a.a in parallel (independent DPP reduce chains),
  // then q -= (2/(s+eps)) * p * a.  Norm computed inline -- no prologue.
  auto step = [&](const float(&a)[16]) {
    float p0 = 0.f, p1 = 0.f, p2 = 0.f, p3 = 0.f;
    float s0 = 0.f, s1 = 0.f, s2 = 0.f, s3 = 0.f;
#pragma unroll
    for (int e = 0; e < 4; ++e) {
      p0 = fmaf(q[e], a[e], p0);
      p1 = fmaf(q[4 + e], a[4 + e], p1);
      p2 = fmaf(q[8 + e], a[8 + e], p2);
      p3 = fmaf(q[12 + e], a[12 + e], p3);
      s0 = fmaf(a[e], a[e], s0);
      s1 = fmaf(a[4 + e], a[4 + e], s1);
      s2 = fmaf(a[8 + e], a[8 + e], s2);
      s3 = fmaf(a[12 + e], a[12 + e], s3);
    }
    const float p = dpp_sum16((p0 + p1) + (p2 + p3));
    const float s = dpp_sum16((s0 + s1) + (s2 + s3));
    const float sc = (2.0f / (s + 1e-16f)) * p;
#pragma unroll
    for (int k = 0; k < 16; ++k) q[k] = fmaf(-sc, a[k], q[k]);
  };

  float A0[16], A1[16], A2[16], A3[16];
  load16(A0, 0); load16(A1, 1); load16(A2, 2); load16(A3, 3);

  // 32 iters x 4 steps = steps 0..127; prefetch 4 deep (~450cy ahead).
  // sched_barrier(0) pins each load between its step and the next step --
  // the compiler cannot sink it to its use 4 steps later (R15: sinking
  // serialized 4 L2 latencies per step = 890cy/step).
  for (int t = 0; t < 32; ++t) {
    const int n4 = 4 * t + 4;
    step(A0); load16(A0, n4);
    __builtin_amdgcn_sched_barrier(0);
    step(A1); load16(A1, n4 + 1);
    __builtin_amdgcn_sched_barrier(0);
    step(A2); load16(A2, n4 + 2);
    __builtin_amdgcn_sched_barrier(0);
    step(A3); load16(A3, n4 + 3);
    __builtin_amdgcn_sched_barrier(0);
  }
  step(A0);  // step 128 (row brow+128, loaded at t=31)

  float4* out = (float4*)(Qc + (long)chunk * 65536 + row * 256 + col0);
#pragma unroll
  for (int i = 0; i < 4; ++i)
    out[i] = make_float4(q[4 * i], q[4 * i + 1], q[4 * i + 2], q[4 * i + 3]);
}

// ---------------- Phase 2: single merge (R8/R13-proven LDS fp32 GEMM) ------
// Qb = bf16( Qc0 * Qc1 ). Grid 64 blocks x 256 thr; 32x32 tile per block,
// 2x2 per thread, K staged via LDS in 64-wide panels.
__launch_bounds__(256)
__global__ void hh_mm(const float* __restrict__ in,
                      unsigned short* __restrict__ outb) {
  const int t = blockIdx.x;
  const int ti = (t >> 3) * 32, tj = (t & 7) * 32;
  const int tid = threadIdx.x;
  const int tx = tid & 15, ty = tid >> 4;
  const float* A = in;            // Qc0
  const float* Bm = in + 65536;   // Qc1

  __shared__ float As[32][68];
  __shared__ float Bs[64][36];

  float acc00 = 0.f, acc01 = 0.f, acc10 = 0.f, acc11 = 0.f;

  for (int k0 = 0; k0 < 256; k0 += 64) {
#pragma unroll
    for (int u0 = 0; u0 < 2048; u0 += 1024) {
      int idx = u0 + tid * 4;
      int rr = idx >> 6, cc = idx & 63;
      *(float4*)&As[rr][cc] = *(const float4*)&A[(ti + rr) * 256 + k0 + cc];
      int kk = idx >> 5, jj = idx & 31;
      *(float4*)&Bs[kk][jj] = *(const float4*)&Bm[(k0 + kk) * 256 + tj + jj];
    }
    __syncthreads();
#pragma unroll 8
    for (int kk = 0; kk < 64; ++kk) {
      float a0 = As[2 * ty][kk], a1 = As[2 * ty + 1][kk];
      float b0 = Bs[kk][2 * tx], b1 = Bs[kk][2 * tx + 1];
      acc00 = fmaf(a0, b0, acc00);
      acc01 = fmaf(a0, b1, acc01);
      acc10 = fmaf(a1, b0, acc10);
      acc11 = fmaf(a1, b1, acc11);
    }
    __syncthreads();
  }

  const int gi = ti + 2 * ty, gj = tj + 2 * tx;
  outb[gi * 256 + gj] = f2bf_rne(acc00);
  outb[gi * 256 + gj + 1] = f2bf_rne(acc01);
  outb[(gi + 1) * 256 + gj] = f2bf_rne(acc10);
  outb[(gi + 1) * 256 + gj + 1] = f2bf_rne(acc11);
}

// ---------------- Phase 3: GEMM --------------------------------------------
// C[M=65536][256] = A[M][K=256](f32, cvt->bf16) * B[N=256][K=256](bf16, BT)
// Block: BM=128, BN=256, BK=32, 512 thr (8 waves). Wave grid 2x4, 64x64/wave.
// LDS 64KB dbuf; XOR-swizzled staging via pre-swizzled GLOBAL source address.
__launch_bounds__(512)
__global__ void hh_gemm(const float* __restrict__ X,
                        const unsigned short* __restrict__ Qb,
                        float* __restrict__ Y) {
  __shared__ __align__(128) char lds[65536];
  const int tid = threadIdx.x;
  const int lane = tid & 63;
  const int wid = tid >> 6;
  const int wm = wid >> 2;  // 0..1
  const int wn = wid & 3;   // 0..3
  const int fr = lane & 15;
  const int fg = lane >> 4;
  const long bm0 = (long)blockIdx.x * 128;

  auto stage = [&](int buf, int kt) {
#pragma unroll
    for (int r2 = 0; r2 < 2; ++r2) {
      int slot = r2 * 512 + tid;
      int row = slot >> 3, seg = slot & 7;
      int ps = seg ^ (row & 7);
      GLOAD_LDS16(X + (bm0 + row) * 256 + kt * 32 + ps * 4,
                  lds + buf * 16384 + slot * 16);
    }
#pragma unroll
    for (int r2 = 0; r2 < 2; ++r2) {
      int slot = r2 * 512 + tid;
      int row = slot >> 2, seg = slot & 3;
      int ps = seg ^ (row & 3);
      GLOAD_LDS16(Qb + row * 256 + kt * 32 + ps * 8,
                  lds + 32768 + buf * 16384 + slot * 16);
    }
  };

  f32x4 acc[4][4];
#pragma unroll
  for (int m = 0; m < 4; ++m)
#pragma unroll
    for (int n = 0; n < 4; ++n) acc[m][n] = (f32x4){0.f, 0.f, 0.f, 0.f};

  stage(0, 0);
  __syncthreads();

  for (int kt = 0; kt < 8; ++kt) {
    const int cur = kt & 1;
    if (kt < 7) stage(cur ^ 1, kt + 1);

    bf16x8 aF[4], bF[4];
#pragma unroll
    for (int m = 0; m < 4; ++m) {
      int row = wm * 64 + m * 16 + fr;
      int s0 = (2 * fg) ^ (row & 7);
      int s1 = (2 * fg + 1) ^ (row & 7);
      const f32x4 x0 = *(const f32x4*)(lds + cur * 16384 + row * 128 + s0 * 16);
      const f32x4 x1 = *(const f32x4*)(lds + cur * 16384 + row * 128 + s1 * 16);
      bf16x8 t;
      t[0] = (short)f2bf_rne(x0[0]);
      t[1] = (short)f2bf_rne(x0[1]);
      t[2] = (short)f2bf_rne(x0[2]);
      t[3] = (short)f2bf_rne(x0[3]);
      t[4] = (short)f2bf_rne(x1[0]);
      t[5] = (short)f2bf_rne(x1[1]);
      t[6] = (short)f2bf_rne(x1[2]);
      t[7] = (short)f2bf_rne(x1[3]);
      aF[m] = t;
    }
#pragma unroll
    for (int n = 0; n < 4; ++n) {
      int row = wn * 64 + n * 16 + fr;
      int ps = fg ^ (row & 3);
      bF[n] = *(const bf16x8*)(lds + 32768 + cur * 16384 + row * 64 + ps * 16);
    }
#pragma unroll
    for (int m = 0; m < 4; ++m)
#pragma unroll
      for (int n = 0; n < 4; ++n)
        acc[m][n] =
            __builtin_amdgcn_mfma_f32_16x16x32_bf16(aF[m], bF[n], acc[m][n], 0, 0, 0);
    __syncthreads();
  }

#pragma unroll
  for (int m = 0; m < 4; ++m)
#pragma unroll
    for (int n = 0; n < 4; ++n)
#pragma unroll
      for (int r = 0; r < 4; ++r) {
        long grow = bm0 + wm * 64 + m * 16 + fg * 4 + r;
        int gcol = wn * 64 + n * 16 + fr;
        Y[grow * 256 + gcol] = acc[m][n][r];
      }
}

// ---------------------------------------------------------------------------
extern "C" void kernel_launch(void* const* d_in, const int* in_sizes, int n_in,
                              void* d_out, int out_size, void* d_ws, size_t ws_size,
                              hipStream_t stream) {
  const float* x = (const float*)d_in[0];      // [65536][256] f32
  const float* vecs = (const float*)d_in[1];   // [258][256] f32
  float* y = (float*)d_out;                    // [65536][256] f32

  unsigned short* Qb = (unsigned short*)d_ws;  // 256x256 bf16 (128KB)
  float* Qc = (float*)d_out;                   // 2 x 256x256 f32 scratch
                                               // (512KB, dead before hh_gemm)

  hh_qchunk<<<128, 64, 0, stream>>>(vecs, Qc);
  hh_mm<<<64, 256, 0, stream>>>(Qc, Qb);
  hh_gemm<<<512, 512, 0, stream>>>(x, Qb, y);
}